// Round 8
// baseline (1238.708 us; speedup 1.0000x reference)
//
#include <hip/hip_runtime.h>

#define NB 4
#define NP 8192
#define NS 1024
#define NK 32
#define CNT_ALL 131072.0f   // NB*NS*NK

typedef float v2f __attribute__((ext_vector_type(2)));

template <int CTRL>
__device__ __forceinline__ unsigned dpp_max_u32(unsigned m)
{
    unsigned o = (unsigned)__builtin_amdgcn_update_dpp((int)m, (int)m, CTRL, 0xF, 0xF, false);
    return (o > m) ? o : m;
}

template <int CTRL>
__device__ __forceinline__ unsigned long long dpp_max_u64(unsigned long long k)
{
    unsigned lo = (unsigned)k, hi = (unsigned)(k >> 32);
    unsigned olo = (unsigned)__builtin_amdgcn_update_dpp((int)lo, (int)lo, CTRL, 0xF, 0xF, false);
    unsigned ohi = (unsigned)__builtin_amdgcn_update_dpp((int)hi, (int)hi, CTRL, 0xF, 0xF, false);
    unsigned long long o = ((unsigned long long)ohi << 32) | (unsigned long long)olo;
    return (o > k) ? o : k;
}

// ---------------------------------------------------------------- FPS
// One block (512 thr, 8 waves) per batch; block NB zeroes BN stat shards.
// Scan loop is pure vector ops (min/max accumulate, NO per-point index
// tracking, NO partial .x/.y writes) -> minimal VALU issue; argmax index is
// recovered post-hoc by the winning lane rescanning its 16 register dists.
// Tie-break == numpy first-max: blocked ownership (lane order = index order),
// ascending j scan, lowest matching lane via ballot/ffs, lowest wave via
// (NP-1-idx) key low word. xyz in LDS as float4 -> 1 ds_read_b128 broadcast
// for the per-iter centroid fetch.
__global__ __launch_bounds__(512, 2) void fps_kernel(const float* __restrict__ xyz,
                                                     float* __restrict__ newxyz,
                                                     float* __restrict__ st)
{
#pragma clang fp contract(off)
    if (blockIdx.x >= NB) {
        for (int i = threadIdx.x; i < 4096; i += 512) st[i] = 0.f;
        return;
    }
    const int b = blockIdx.x;
    const int tid = threadIdx.x;
    const int lane = tid & 63;
    const int w = tid >> 6;                 // 8 waves
    const float* xb = xyz + (size_t)b * NP * 3;

    __shared__ float4 s_p4[NP];                         // 128 KB
    __shared__ unsigned long long s_kv[2][8];

#pragma unroll
    for (int k = 0; k < 16; ++k) {
        const int i = k * 512 + tid;
        s_p4[i] = make_float4(xb[3 * i + 0], xb[3 * i + 1], xb[3 * i + 2], 0.f);
    }
    __syncthreads();

    v2f px[8], py[8], pz[8], dist[8];
    const int base = tid << 4;
#pragma unroll
    for (int m = 0; m < 8; ++m) {
        const int p0 = base + 2 * m;
        const float4 a = s_p4[p0];
        const float4 c = s_p4[p0 + 1];
        px[m] = v2f{a.x, c.x};
        py[m] = v2f{a.y, c.y};
        pz[m] = v2f{a.z, c.z};
        dist[m] = v2f{1e10f, 1e10f};
    }
    float cx = s_p4[0].x, cy = s_p4[0].y, cz = s_p4[0].z;
    float* ob = newxyz + (size_t)b * NS * 3;

    for (int it = 0; it < NS; ++it) {
        if (tid == 0) { ob[it * 3 + 0] = cx; ob[it * 3 + 1] = cy; ob[it * 3 + 2] = cz; }
        const v2f cxx = v2f{cx, cx}, cyy = v2f{cy, cy}, czz = v2f{cz, cz};
        v2f bdv = v2f{-1.0f, -1.0f};
#pragma unroll
        for (int m = 0; m < 8; ++m) {
            v2f dx = px[m] - cxx, dy = py[m] - cyy, dz = pz[m] - czz;
            v2f d = (dx * dx + dy * dy) + dz * dz;      // numpy op order, no fma
            v2f dj = __builtin_elementwise_min(dist[m], d);
            dist[m] = dj;
            bdv = __builtin_elementwise_max(bdv, dj);
        }
        const float bd = fmaxf(bdv.x, bdv.y);
        // wave max of dist bits (bd >= 0 so float bits order-preserving as u32)
        const unsigned ub = __float_as_uint(bd);
        unsigned m0 = dpp_max_u32<0xB1>(ub);    // quad_perm xor1
        m0 = dpp_max_u32<0x4E>(m0);             // quad_perm xor2
        m0 = dpp_max_u32<0x141>(m0);            // row_half_mirror
        m0 = dpp_max_u32<0x140>(m0);            // row_mirror
        m0 = dpp_max_u32<0x142>(m0);            // row_bcast15
        m0 = dpp_max_u32<0x143>(m0);            // row_bcast31 -> lane63 = wave max
        const unsigned maxbits = (unsigned)__builtin_amdgcn_readlane((int)m0, 63);
        const unsigned long long bm = __ballot(ub == maxbits);
        const int srclane = __ffsll(bm) - 1;    // lowest lane = lowest index
        if (lane == srclane) {
            // recover smallest local index j with dist == bd (bit-exact member)
            int j = 0;
#pragma unroll
            for (int m = 7; m >= 0; --m) {
                if (dist[m].y == bd) j = 2 * m + 1;
                if (dist[m].x == bd) j = 2 * m;
            }
            const int wbi = base + j;
            s_kv[it & 1][w] = ((unsigned long long)maxbits << 32)
                            | (unsigned)(NP - 1 - wbi);   // bigger low = smaller idx
        }
        __syncthreads();
        unsigned long long kv = s_kv[it & 1][lane & 7];
        kv = dpp_max_u64<0xB1>(kv);
        kv = dpp_max_u64<0x4E>(kv);
        kv = dpp_max_u64<0x141>(kv);            // all 8 wave keys -> uniform
        const int fi = NP - 1 - (int)(unsigned)(kv & 0xFFFFFFFFull);
        const float4 c4 = s_p4[fi];             // single b128 broadcast read
        cx = c4.x; cy = c4.y; cz = c4.z;
    }
}

// compute BN scale/shift for channel c from 8-sharded sums
__device__ __forceinline__ void bn_coef(const float* __restrict__ sums,
                                        const float* __restrict__ sqs,
                                        const float* __restrict__ g,
                                        const float* __restrict__ be,
                                        int C, int c, float& sc, float& sh)
{
    float s = 0.f, q = 0.f;
#pragma unroll
    for (int k = 0; k < 8; ++k) { s += sums[k * C + c]; q += sqs[k * C + c]; }
    const float mean = s / CNT_ALL;
    const float var = q / CNT_ALL - mean * mean;
    sc = g[c] / sqrtf(var + 1e-5f);
    sh = be[c] - mean * sc;
}

// ---------------------------------------------------------------- Phase A: ball query + linear1 + stats1
__global__ __launch_bounds__(256) void phaseA_kernel(
    const float* __restrict__ xyz, const float* __restrict__ pts,
    const float* __restrict__ newxyz,
    const float* __restrict__ w1, const float* __restrict__ b1,
    float* __restrict__ y1, float* __restrict__ st)
{
    __shared__ int   s_ball[8][NK];
    __shared__ float s_feat[256][20];
    __shared__ float s_ps[256], s_pq[256];
    float* sums1 = st;
    float* sqs1 = st + 512;

    const int tid = threadIdx.x;
    const int bk = blockIdx.x;
    const int lane = tid & 63;
    const int wv_id = tid >> 6;

    const int b = (8 * bk) >> 10;
    const float* xb = xyz + (size_t)b * NP * 3;
    const float rr = (float)(0.2 * 0.2);
    for (int r = 0; r < 2; ++r) {
        const int lg = 2 * wv_id + r;
        const int sg = 8 * bk + lg;
        const float cx = newxyz[sg * 3 + 0];
        const float cy = newxyz[sg * 3 + 1];
        const float cz = newxyz[sg * 3 + 2];
        int cnt = 0;
        for (int base = 0; base < NP && cnt < NK; base += 64) {
            const int p = base + lane;
            float dx = xb[p * 3 + 0] - cx;
            float dy = xb[p * 3 + 1] - cy;
            float dz = xb[p * 3 + 2] - cz;
            float d = __fadd_rn(__fadd_rn(__fmul_rn(dx, dx), __fmul_rn(dy, dy)),
                                __fmul_rn(dz, dz));
            bool in = (d <= rr);
            unsigned long long mask = __ballot(in);
            int before = __popcll(mask & ((1ull << lane) - 1ull));
            int pos = cnt + before;
            if (in && pos < NK) s_ball[lg][pos] = p;
            cnt += (int)__popcll(mask);
        }
        cnt = min(cnt, NK);
        const int v0 = s_ball[lg][0];       // cnt >= 1 (centroid itself in-radius)
        if (lane < NK && lane >= cnt) s_ball[lg][lane] = v0;
    }
    __syncthreads();
    {   // stage features: thread t -> row t
        const int lg = tid >> 5, k = tid & 31;
        const int id = s_ball[lg][k];
        const int sg = 8 * bk + lg;
        const float* pp = xyz + ((size_t)b * NP + id) * 3;
        const float* cp = newxyz + (size_t)sg * 3;
        float* f = s_feat[tid];
        f[0] = pp[0] - cp[0];
        f[1] = pp[1] - cp[1];
        f[2] = pp[2] - cp[2];
        const float4* q4 = (const float4*)(pts + ((size_t)b * NP + id) * 16);
#pragma unroll
        for (int i = 0; i < 4; ++i) {
            float4 v = q4[i];
            f[3 + 4 * i + 0] = v.x; f[3 + 4 * i + 1] = v.y;
            f[3 + 4 * i + 2] = v.z; f[3 + 4 * i + 3] = v.w;
        }
        f[19] = 0.f;
    }
    __syncthreads();
    const int c = tid & 63, rg = tid >> 6;
    float wv[20];
#pragma unroll
    for (int j = 0; j < 19; ++j) wv[j] = w1[c * 19 + j];
    wv[19] = 0.f;
    const float bs = b1[c];
    float s = 0.f, q = 0.f;
    for (int r = 0; r < 64; ++r) {
        const int row = rg * 64 + r;
        const float4* f4 = (const float4*)s_feat[row];
        float acc = bs;
#pragma unroll
        for (int j4 = 0; j4 < 5; ++j4) {
            float4 v = f4[j4];
            acc += wv[4*j4+0]*v.x + wv[4*j4+1]*v.y + wv[4*j4+2]*v.z + wv[4*j4+3]*v.w;
        }
        y1[((size_t)256 * bk + row) * 64 + c] = acc;
        s += acc; q += acc * acc;
    }
    s_ps[tid] = s; s_pq[tid] = q;
    __syncthreads();
    if (rg == 0) {
        float ts = s_ps[c] + s_ps[64 + c] + s_ps[128 + c] + s_ps[192 + c];
        float tq = s_pq[c] + s_pq[64 + c] + s_pq[128 + c] + s_pq[192 + c];
        atomicAdd(&sums1[(bk & 7) * 64 + c], ts);
        atomicAdd(&sqs1[(bk & 7) * 64 + c], tq);
    }
}

// ---------------------------------------------------------------- Phase B: BN1+ReLU + linear2 + stats2
__global__ __launch_bounds__(256) void phaseB_kernel(
    const float* __restrict__ y1,
    const float* __restrict__ g1, const float* __restrict__ be1,
    const float* __restrict__ w2, const float* __restrict__ b2,
    float* __restrict__ y2, float* __restrict__ st)
{
    __shared__ float x_lds[128 * 64];       // 32 KB
    __shared__ float s_sc[64], s_sh[64];
    __shared__ float s_ps[256], s_pq[256];
    const float* sums1 = st;
    const float* sqs1 = st + 512;
    float* sums2 = st + 1024;
    float* sqs2 = st + 1536;

    const int tid = threadIdx.x;
    const int bk = blockIdx.x;
    if (tid < 64) {
        float sc, sh;
        bn_coef(sums1, sqs1, g1, be1, 64, tid, sc, sh);
        s_sc[tid] = sc; s_sh[tid] = sh;
    }
    __syncthreads();
    const int c = tid & 63, rg = tid >> 6;
    float wv[64];
#pragma unroll
    for (int j = 0; j < 64; ++j) wv[j] = w2[c * 64 + j];
    const float bs = b2[c];
    float s = 0.f, q = 0.f;
    for (int half = 0; half < 2; ++half) {
        const size_t row0 = (size_t)256 * bk + 128 * half;
        const float4* y1g = (const float4*)(y1 + row0 * 64);
        float4* xl4 = (float4*)x_lds;
#pragma unroll
        for (int i = 0; i < 8; ++i) {
            const int slot = i * 256 + tid;
            float4 v = y1g[slot];
            const int c4 = (slot & 15) * 4;
            float4 o;
            o.x = fmaxf(v.x * s_sc[c4+0] + s_sh[c4+0], 0.f);
            o.y = fmaxf(v.y * s_sc[c4+1] + s_sh[c4+1], 0.f);
            o.z = fmaxf(v.z * s_sc[c4+2] + s_sh[c4+2], 0.f);
            o.w = fmaxf(v.w * s_sc[c4+3] + s_sh[c4+3], 0.f);
            xl4[slot] = o;
        }
        __syncthreads();
        for (int r = 0; r < 32; ++r) {
            const int row = rg * 32 + r;
            const float4* x4 = (const float4*)(x_lds + row * 64);
            float acc = bs;
#pragma unroll
            for (int j4 = 0; j4 < 16; ++j4) {
                float4 v = x4[j4];
                acc += wv[4*j4+0]*v.x + wv[4*j4+1]*v.y + wv[4*j4+2]*v.z + wv[4*j4+3]*v.w;
            }
            y2[(row0 + row) * 64 + c] = acc;
            s += acc; q += acc * acc;
        }
        __syncthreads();
    }
    s_ps[tid] = s; s_pq[tid] = q;
    __syncthreads();
    if (rg == 0) {
        float ts = s_ps[c] + s_ps[64 + c] + s_ps[128 + c] + s_ps[192 + c];
        float tq = s_pq[c] + s_pq[64 + c] + s_pq[128 + c] + s_pq[192 + c];
        atomicAdd(&sums2[(bk & 7) * 64 + c], ts);
        atomicAdd(&sqs2[(bk & 7) * 64 + c], tq);
    }
}

// ---------------------------------------------------------------- Phase C: BN2+ReLU + linear3 + stats3
__global__ __launch_bounds__(256) void phaseC_kernel(
    const float* __restrict__ y2,
    const float* __restrict__ g2, const float* __restrict__ be2,
    const float* __restrict__ w3, const float* __restrict__ b3,
    float* __restrict__ st)
{
    __shared__ float s_x[NK * 64];          // 8 KB
    __shared__ float s_sc[64], s_sh[64];
    __shared__ float s_p3s[256], s_p3q[256];
    const float* sums2 = st + 1024;
    const float* sqs2 = st + 1536;
    float* sums3 = st + 2048;
    float* sqs3 = st + 3072;

    const int tid = threadIdx.x;
    const int bk = blockIdx.x;
    if (tid < 64) {
        float sc, sh;
        bn_coef(sums2, sqs2, g2, be2, 64, tid, sc, sh);
        s_sc[tid] = sc; s_sh[tid] = sh;
    }
    __syncthreads();
    const int c = tid & 127, rg = tid >> 7;
    float wv[64];
#pragma unroll
    for (int j = 0; j < 64; ++j) wv[j] = w3[c * 64 + j];
    const float bs = b3[c];
    float s = 0.f, q = 0.f;
    for (int gi = 0; gi < 8; ++gi) {
        const size_t grow0 = (size_t)256 * bk + 32 * gi;
        const float4* y2g = (const float4*)(y2 + grow0 * 64);
        float4* sx4 = (float4*)s_x;
#pragma unroll
        for (int i = 0; i < 2; ++i) {
            const int slot = i * 256 + tid;
            float4 v = y2g[slot];
            const int c4 = (slot & 15) * 4;
            float4 o;
            o.x = fmaxf(v.x * s_sc[c4+0] + s_sh[c4+0], 0.f);
            o.y = fmaxf(v.y * s_sc[c4+1] + s_sh[c4+1], 0.f);
            o.z = fmaxf(v.z * s_sc[c4+2] + s_sh[c4+2], 0.f);
            o.w = fmaxf(v.w * s_sc[c4+3] + s_sh[c4+3], 0.f);
            sx4[slot] = o;
        }
        __syncthreads();
        for (int r = 0; r < 16; ++r) {
            const int row = rg * 16 + r;
            const float4* x4 = (const float4*)(s_x + row * 64);
            float acc = bs;
#pragma unroll
            for (int j4 = 0; j4 < 16; ++j4) {
                float4 v = x4[j4];
                acc += wv[4*j4+0]*v.x + wv[4*j4+1]*v.y + wv[4*j4+2]*v.z + wv[4*j4+3]*v.w;
            }
            s += acc; q += acc * acc;
        }
        __syncthreads();
    }
    s_p3s[rg * 128 + c] = s; s_p3q[rg * 128 + c] = q;
    __syncthreads();
    if (rg == 0) {
        atomicAdd(&sums3[(bk & 7) * 128 + c], s_p3s[c] + s_p3s[128 + c]);
        atomicAdd(&sqs3[(bk & 7) * 128 + c], s_p3q[c] + s_p3q[128 + c]);
    }
}

// ---------------------------------------------------------------- Phase D: BN2+ReLU + linear3 + BN3 + ReLU + maxpool
__global__ __launch_bounds__(256) void phaseD_kernel(
    const float* __restrict__ y2,
    const float* __restrict__ g2, const float* __restrict__ be2,
    const float* __restrict__ g3, const float* __restrict__ be3,
    const float* __restrict__ w3, const float* __restrict__ b3,
    const float* __restrict__ st, float* __restrict__ out_np)
{
    __shared__ float s_x[NK * 64];
    __shared__ float s_sc[64], s_sh[64];
    __shared__ float s_fm[256];
    const float* sums2 = st + 1024;
    const float* sqs2 = st + 1536;
    const float* sums3 = st + 2048;
    const float* sqs3 = st + 3072;

    const int tid = threadIdx.x;
    const int bk = blockIdx.x;
    if (tid < 64) {
        float sc, sh;
        bn_coef(sums2, sqs2, g2, be2, 64, tid, sc, sh);
        s_sc[tid] = sc; s_sh[tid] = sh;
    }
    const int c = tid & 127, rg = tid >> 7;
    float sc3, sh3;
    bn_coef(sums3, sqs3, g3, be3, 128, c, sc3, sh3);
    __syncthreads();
    float wv[64];
#pragma unroll
    for (int j = 0; j < 64; ++j) wv[j] = w3[c * 64 + j];
    const float bs = b3[c];
    for (int gi = 0; gi < 8; ++gi) {
        const size_t grow0 = (size_t)256 * bk + 32 * gi;
        const float4* y2g = (const float4*)(y2 + grow0 * 64);
        float4* sx4 = (float4*)s_x;
#pragma unroll
        for (int i = 0; i < 2; ++i) {
            const int slot = i * 256 + tid;
            float4 v = y2g[slot];
            const int c4 = (slot & 15) * 4;
            float4 o;
            o.x = fmaxf(v.x * s_sc[c4+0] + s_sh[c4+0], 0.f);
            o.y = fmaxf(v.y * s_sc[c4+1] + s_sh[c4+1], 0.f);
            o.z = fmaxf(v.z * s_sc[c4+2] + s_sh[c4+2], 0.f);
            o.w = fmaxf(v.w * s_sc[c4+3] + s_sh[c4+3], 0.f);
            sx4[slot] = o;
        }
        __syncthreads();
        float m = 0.f;                       // relu >= 0
        for (int r = 0; r < 16; ++r) {
            const int row = rg * 16 + r;
            const float4* x4 = (const float4*)(s_x + row * 64);
            float acc = bs;
#pragma unroll
            for (int j4 = 0; j4 < 16; ++j4) {
                float4 v = x4[j4];
                acc += wv[4*j4+0]*v.x + wv[4*j4+1]*v.y + wv[4*j4+2]*v.z + wv[4*j4+3]*v.w;
            }
            float rv = fmaxf(acc * sc3 + sh3, 0.f);
            m = fmaxf(m, rv);
        }
        s_fm[rg * 128 + c] = m;
        __syncthreads();
        if (rg == 0)
            out_np[(size_t)(8 * bk + gi) * 128 + c] = fmaxf(s_fm[c], s_fm[128 + c]);
        __syncthreads();
    }
}

// ---------------------------------------------------------------- host launch
extern "C" void kernel_launch(void* const* d_in, const int* in_sizes, int n_in,
                              void* d_out, int out_size, void* d_ws, size_t ws_size,
                              hipStream_t stream)
{
    (void)in_sizes; (void)n_in; (void)out_size;
    const float* xyz = (const float*)d_in[0];
    const float* pts = (const float*)d_in[1];
    const float* w1 = (const float*)d_in[2];
    const float* b1 = (const float*)d_in[3];
    const float* g1 = (const float*)d_in[4];
    const float* be1 = (const float*)d_in[5];
    const float* w2 = (const float*)d_in[6];
    const float* b2 = (const float*)d_in[7];
    const float* g2 = (const float*)d_in[8];
    const float* be2 = (const float*)d_in[9];
    const float* w3 = (const float*)d_in[10];
    const float* b3 = (const float*)d_in[11];
    const float* g3 = (const float*)d_in[12];
    const float* be3 = (const float*)d_in[13];

    float* out = (float*)d_out;
    float* newxyz = out;              // 4*1024*3
    float* newpts = out + NB * NS * 3;

    float* y1 = (float*)d_ws;                          // 8388608 f32
    float* y2 = y1 + 8388608;
    float* st = y2 + 8388608;                          // 4096 f32 stat shards
    const size_t needed = (2ull * 8388608ull + 4096ull) * 4ull;
    if (ws_size < needed) return;

    fps_kernel<<<NB + 1, 512, 0, stream>>>(xyz, newxyz, st);
    phaseA_kernel<<<512, 256, 0, stream>>>(xyz, pts, newxyz, w1, b1, y1, st);
    phaseB_kernel<<<512, 256, 0, stream>>>(y1, g1, be1, w2, b2, y2, st);
    phaseC_kernel<<<512, 256, 0, stream>>>(y2, g2, be2, w3, b3, st);
    phaseD_kernel<<<512, 256, 0, stream>>>(y2, g2, be2, g3, be3, w3, b3, st, newpts);
}